// Round 3
// baseline (3438.382 us; speedup 1.0000x reference)
//
#include <hip/hip_runtime.h>
#include <hip/hip_bf16.h>

#define NROW 10000
#define DIM 128
#define NP 10048          // rows padded to multiple of 64
#define KSEL 15
#define JC 4              // j-chunks per matrix
#define NTILES (NP / 16)  // 628 j-tiles of 16

typedef __attribute__((ext_vector_type(4))) float f32x4;
typedef __attribute__((ext_vector_type(8))) short s16x8;
using bf16_t = __hip_bfloat16;

// ---------------------------------------------------------------- convert
// One wave per row: f32 -> bf16, row squared-norm, pad rows zero / sq=1e30.
__global__ __launch_bounds__(256)
void knn_convert(const float* __restrict__ x0, const float* __restrict__ x1,
                 bf16_t* __restrict__ xb, float* __restrict__ sq,
                 unsigned* __restrict__ counter)
{
    if (blockIdx.x == 0 && threadIdx.x == 0) *counter = 0u;
    const int rg   = blockIdx.x * 4 + (threadIdx.x >> 6);
    const int lane = threadIdx.x & 63;
    if (rg >= 2 * NP) return;
    const int m = rg >= NP ? 1 : 0;
    const int r = rg - m * NP;
    const float* src = m ? x1 : x0;
    bf16_t* dst = xb + ((size_t)m * NP + (size_t)r) * DIM;

    float2 v = make_float2(0.f, 0.f);
    float  s = 0.f;
    if (r < NROW) {
        v = *(const float2*)(src + (size_t)r * DIM + lane * 2);
        s = v.x * v.x + v.y * v.y;
    }
    dst[lane * 2]     = __float2bfloat16(v.x);
    dst[lane * 2 + 1] = __float2bfloat16(v.y);
    #pragma unroll
    for (int off = 32; off; off >>= 1) s += __shfl_down(s, off);
    if (lane == 0) sq[m * NP + r] = (r < NROW) ? s : 1e30f;
}

// ---------------------------------------------------------------- main
// Block: 4 waves, each wave owns 16 i-rows (B operand in regs) and streams a
// j-chunk. C[j][i] = dot(Xj, Xi) - 0.5*sq[j] via MFMA C-in. Per-lane sorted
// top-15 (i fixed per lane = lane&15). 4 lane-group lists merged via LDS.
__global__ __launch_bounds__(256)
void knn_topk(const bf16_t* __restrict__ xb, const float* __restrict__ sq,
              float* __restrict__ pvals, int* __restrict__ pidx)
{
    __shared__ float lv[4][64][KSEL];
    __shared__ int   lx[4][64][KSEL];

    const int m     = blockIdx.z;
    const int chunk = blockIdx.y;
    const int ib    = blockIdx.x * 64;
    const int wave  = threadIdx.x >> 6;
    const int lane  = threadIdx.x & 63;
    const int li    = lane & 15;
    const int g     = lane >> 4;

    const bf16_t* X  = xb + (size_t)m * NP * DIM;
    const float*  SQ = sq + m * NP;

    const int i  = ib + wave * 16 + li;
    const int ic = i < NROW ? i : NROW - 1;

    // B fragments: lane holds B[k = kk*32 + g*8 + e][col = li] = X[i][k]
    s16x8 bfr[4];
    #pragma unroll
    for (int kk = 0; kk < 4; ++kk)
        bfr[kk] = *(const s16x8*)(X + (size_t)ic * DIM + kk * 32 + g * 8);

    float vals[KSEL]; int idxs[KSEL];
    #pragma unroll
    for (int t = 0; t < KSEL; ++t) { vals[t] = -1e38f; idxs[t] = -1; }

    const int t0 = (chunk * NTILES) / JC;
    const int t1 = ((chunk + 1) * NTILES) / JC;

    for (int t = t0; t < t1; ++t) {
        const int jt = t * 16;
        const f32x4 sqv = *(const f32x4*)(SQ + jt + g * 4);
        f32x4 acc;
        #pragma unroll
        for (int r = 0; r < 4; ++r) acc[r] = -0.5f * sqv[r];
        #pragma unroll
        for (int kk = 0; kk < 4; ++kk) {
            // A fragment: lane holds A[row = li][k = kk*32 + g*8 + e] = X[jt+li][k]
            const s16x8 afr = *(const s16x8*)(X + (size_t)(jt + li) * DIM + kk * 32 + g * 8);
            acc = __builtin_amdgcn_mfma_f32_16x16x32_bf16(afr, bfr[kk], acc, 0, 0, 0);
        }
        // C/D: col = li (the i), row = g*4 + r (the j-local)
        #pragma unroll
        for (int r = 0; r < 4; ++r) {
            const float key = acc[r];
            if (key > vals[KSEL - 1]) {
                vals[KSEL - 1] = key;
                idxs[KSEL - 1] = jt + g * 4 + r;
                #pragma unroll
                for (int mm = KSEL - 1; mm > 0; --mm) {
                    const bool c = vals[mm] > vals[mm - 1];
                    const float va = c ? vals[mm] : vals[mm - 1];
                    const float vb = c ? vals[mm - 1] : vals[mm];
                    const int   ja = c ? idxs[mm] : idxs[mm - 1];
                    const int   jb = c ? idxs[mm - 1] : idxs[mm];
                    vals[mm - 1] = va; vals[mm] = vb;
                    idxs[mm - 1] = ja; idxs[mm] = jb;
                }
            }
        }
    }

    #pragma unroll
    for (int t = 0; t < KSEL; ++t) { lv[wave][lane][t] = vals[t]; lx[wave][lane][t] = idxs[t]; }
    __syncthreads();

    // 4-way merge of the lane-group lists for this i; write sorted 15.
    if (g == 0 && i < NROW) {
        int p0 = 0, p1 = 0, p2 = 0, p3 = 0;
        float v0 = lv[wave][li][0];
        float v1 = lv[wave][16 + li][0];
        float v2 = lv[wave][32 + li][0];
        float v3 = lv[wave][48 + li][0];
        float* ov = pvals + (((size_t)m * JC + chunk) * NROW + i) * KSEL;
        int*   oi = pidx  + (((size_t)m * JC + chunk) * NROW + i) * KSEL;
        #pragma unroll
        for (int t = 0; t < KSEL; ++t) {
            float bv = v0; int bg = 0;
            if (v1 > bv) { bv = v1; bg = 1; }
            if (v2 > bv) { bv = v2; bg = 2; }
            if (v3 > bv) { bv = v3; bg = 3; }
            int oidx;
            if      (bg == 0) { oidx = lx[wave][li][p0];      p0++; v0 = p0 < KSEL ? lv[wave][li][p0]      : -1e38f; }
            else if (bg == 1) { oidx = lx[wave][16 + li][p1]; p1++; v1 = p1 < KSEL ? lv[wave][16 + li][p1] : -1e38f; }
            else if (bg == 2) { oidx = lx[wave][32 + li][p2]; p2++; v2 = p2 < KSEL ? lv[wave][32 + li][p2] : -1e38f; }
            else              { oidx = lx[wave][48 + li][p3]; p3++; v3 = p3 < KSEL ? lv[wave][48 + li][p3] : -1e38f; }
            ov[t] = bv; oi[t] = oidx;
        }
    }
}

// ---------------------------------------------------------------- merge + count
__global__ __launch_bounds__(256)
void knn_merge_count(const float* __restrict__ pvals, const int* __restrict__ pidx,
                     unsigned* __restrict__ counter)
{
    __shared__ int wsum[4];
    const int i    = blockIdx.x * 256 + threadIdx.x;
    const int lane = threadIdx.x & 63;
    const int wave = threadIdx.x >> 6;

    int cnt = 0;
    if (i < NROW) {
        int ida[KSEL], idb[KSEL];
        #pragma unroll
        for (int m = 0; m < 2; ++m) {
            const float* pv = pvals + (size_t)m * JC * NROW * KSEL;
            const int*   px = pidx  + (size_t)m * JC * NROW * KSEL;
            const float* V0 = pv + ((size_t)0 * NROW + i) * KSEL;
            const float* V1 = pv + ((size_t)1 * NROW + i) * KSEL;
            const float* V2 = pv + ((size_t)2 * NROW + i) * KSEL;
            const float* V3 = pv + ((size_t)3 * NROW + i) * KSEL;
            const int* X0 = px + ((size_t)0 * NROW + i) * KSEL;
            const int* X1 = px + ((size_t)1 * NROW + i) * KSEL;
            const int* X2 = px + ((size_t)2 * NROW + i) * KSEL;
            const int* X3 = px + ((size_t)3 * NROW + i) * KSEL;
            int p0 = 0, p1 = 0, p2 = 0, p3 = 0;
            float v0 = V0[0], v1 = V1[0], v2 = V2[0], v3 = V3[0];
            int* out = (m == 0) ? ida : idb;
            #pragma unroll
            for (int t = 0; t < KSEL; ++t) {
                float bv = v0; int bg = 0;
                if (v1 > bv) { bv = v1; bg = 1; }
                if (v2 > bv) { bv = v2; bg = 2; }
                if (v3 > bv) { bv = v3; bg = 3; }
                if      (bg == 0) { out[t] = X0[p0]; p0++; v0 = p0 < KSEL ? V0[p0] : -1e38f; }
                else if (bg == 1) { out[t] = X1[p1]; p1++; v1 = p1 < KSEL ? V1[p1] : -1e38f; }
                else if (bg == 2) { out[t] = X2[p2]; p2++; v2 = p2 < KSEL ? V2[p2] : -1e38f; }
                else              { out[t] = X3[p3]; p3++; v3 = p3 < KSEL ? V3[p3] : -1e38f; }
            }
        }
        #pragma unroll
        for (int a = 0; a < KSEL; ++a)
            #pragma unroll
            for (int b = 0; b < KSEL; ++b)
                cnt += (ida[a] == idb[b]) ? 1 : 0;
    }

    #pragma unroll
    for (int off = 32; off; off >>= 1) cnt += __shfl_down(cnt, off);
    if (lane == 0) wsum[wave] = cnt;
    __syncthreads();
    if (threadIdx.x == 0)
        atomicAdd(counter, (unsigned)(wsum[0] + wsum[1] + wsum[2] + wsum[3]));
}

__global__ void knn_finalize(const unsigned* __restrict__ counter, float* __restrict__ out)
{
    out[0] = 1.0f - (float)(*counter) / (float)(NROW * KSEL);
}

// ---------------------------------------------------------------- launch
extern "C" void kernel_launch(void* const* d_in, const int* in_sizes, int n_in,
                              void* d_out, int out_size, void* d_ws, size_t ws_size,
                              hipStream_t stream)
{
    (void)in_sizes; (void)n_in; (void)out_size; (void)ws_size;
    const float* x0 = (const float*)d_in[0];
    const float* x1 = (const float*)d_in[1];
    float* out = (float*)d_out;

    char* ws = (char*)d_ws;
    size_t off = 0;
    bf16_t* xb = (bf16_t*)(ws + off); off += (size_t)2 * NP * DIM * sizeof(bf16_t); // 5,144,576
    float*  sq = (float*)(ws + off);  off += (size_t)2 * NP * sizeof(float);        // 80,384
    off = (off + 255) & ~(size_t)255;
    float* pvals = (float*)(ws + off); off += (size_t)2 * JC * NROW * KSEL * sizeof(float); // 4.8 MB
    int*   pidx  = (int*)(ws + off);   off += (size_t)2 * JC * NROW * KSEL * sizeof(int);   // 4.8 MB
    off = (off + 255) & ~(size_t)255;
    unsigned* counter = (unsigned*)(ws + off);

    knn_convert<<<(2 * NP) / 4, 256, 0, stream>>>(x0, x1, xb, sq, counter);
    knn_topk<<<dim3(NP / 64, JC, 2), 256, 0, stream>>>(xb, sq, pvals, pidx);
    knn_merge_count<<<(NROW + 255) / 256, 256, 0, stream>>>(pvals, pidx, counter);
    knn_finalize<<<1, 1, 0, stream>>>(counter, out);
}

// Round 4
// 405.626 us; speedup vs baseline: 8.4767x; 8.4767x over previous
//
#include <hip/hip_runtime.h>
#include <hip/hip_bf16.h>
#include <stdint.h>

#define NROW 10000
#define DIM 128
#define NP 10048           // rows padded to multiple of 64
#define KSEL 15
#define JC 4               // j-chunks per matrix
#define NTILES (NP / 16)   // 628 j-tiles of 16
#define TPC (NTILES / JC)  // 157 tiles per chunk

typedef __attribute__((ext_vector_type(4))) float f32x4;
typedef __attribute__((ext_vector_type(8))) short s16x8;
using bf16_t = __hip_bfloat16;

// ---------------------------------------------------------------- convert
// One wave per row: f32 -> bf16 (packed u32 stores), row squared-norm.
// Pad rows: zero data, sq = 1e30 (their packed key clamps to 1.0 -> never top-15).
__global__ __launch_bounds__(256)
void knn_convert(const float* __restrict__ x0, const float* __restrict__ x1,
                 bf16_t* __restrict__ xb, float* __restrict__ sq,
                 unsigned* __restrict__ counter)
{
    if (blockIdx.x == 0 && threadIdx.x == 0) *counter = 0u;
    const int rg   = blockIdx.x * 4 + (threadIdx.x >> 6);
    const int lane = threadIdx.x & 63;
    if (rg >= 2 * NP) return;
    const int m = rg >= NP ? 1 : 0;
    const int r = rg - m * NP;
    const float* src = m ? x1 : x0;
    uint32_t* dst = (uint32_t*)(xb + ((size_t)m * NP + (size_t)r) * DIM);

    float2 v = make_float2(0.f, 0.f);
    float  s = 0.f;
    if (r < NROW) {
        v = *(const float2*)(src + (size_t)r * DIM + lane * 2);
        s = v.x * v.x + v.y * v.y;
    }
    const uint32_t lo = (uint32_t)__bfloat16_as_ushort(__float2bfloat16(v.x));
    const uint32_t hi = (uint32_t)__bfloat16_as_ushort(__float2bfloat16(v.y));
    dst[lane] = lo | (hi << 16);
    #pragma unroll
    for (int off = 32; off; off >>= 1) s += __shfl_down(s, off);
    if (lane == 0) sq[m * NP + r] = (r < NROW) ? s : 1e30f;
}

// ---------------------------------------------------------------- main
// Key = dot(Xj,Xi) - 0.5*sq[j] + 1024 (bias folded into MFMA C-in), clamped >=1,
// packed as monotonic u32 with 10-bit chunk-local index in the low bits.
// Branchless top-15 per lane via 14x v_med3_u32 + 1 umax (descending list in
// 15 NAMED registers -> no arrays, no scratch spill).
#define INS(k, hi, lo) asm("v_med3_u32 %0, %1, %2, %0" : "+v"(lo) : "v"(k), "v"(hi))

__global__ __launch_bounds__(256)
void knn_topk(const bf16_t* __restrict__ xb, const float* __restrict__ sq,
              uint32_t* __restrict__ pkey, int* __restrict__ pidx)
{
    __shared__ uint32_t lv[4][64][KSEL];
    __shared__ int      lx[4][64][KSEL];

    const int m     = blockIdx.z;
    const int chunk = blockIdx.y;
    const int ib    = blockIdx.x * 64;
    const int wave  = threadIdx.x >> 6;
    const int lane  = threadIdx.x & 63;
    const int li    = lane & 15;
    const int g     = lane >> 4;

    const bf16_t* X  = xb + (size_t)m * NP * DIM;
    const float*  SQ = sq + m * NP;

    const int i  = ib + wave * 16 + li;
    const int ic = i < NROW ? i : NROW - 1;

    // B fragments: lane holds B[k = kk*32 + g*8 + e][col = li] = X[i][k]
    s16x8 bfr[4];
    #pragma unroll
    for (int kk = 0; kk < 4; ++kk)
        bfr[kk] = *(const s16x8*)(X + (size_t)ic * DIM + kk * 32 + g * 8);

    uint32_t q0 = 0, q1 = 0, q2 = 0, q3 = 0, q4 = 0, q5 = 0, q6 = 0, q7 = 0,
             q8 = 0, q9 = 0, q10 = 0, q11 = 0, q12 = 0, q13 = 0, q14 = 0;

    const int t0 = chunk * TPC;

    for (int tl = 0; tl < TPC; ++tl) {
        const int jt = (t0 + tl) * 16;
        const f32x4 sqv = *(const f32x4*)(SQ + jt + g * 4);
        f32x4 acc;
        #pragma unroll
        for (int r = 0; r < 4; ++r) acc[r] = fmaf(sqv[r], -0.5f, 1024.0f);
        #pragma unroll
        for (int kk = 0; kk < 4; ++kk) {
            // A fragment: lane holds A[row = li][k = kk*32 + g*8 + e] = X[jt+li][k]
            const s16x8 afr = *(const s16x8*)(X + (size_t)(jt + li) * DIM + kk * 32 + g * 8);
            acc = __builtin_amdgcn_mfma_f32_16x16x32_bf16(afr, bfr[kk], acc, 0, 0, 0);
        }
        // C/D: col = li (the i), row = g*4 + r (the j-local).
        const uint32_t idxb = (uint32_t)(tl << 2);
        #pragma unroll
        for (int r = 0; r < 4; ++r) {
            const float f = fmaxf(acc[r], 1.0f);          // padded j -> 1.0, never selected
            const uint32_t b = __float_as_uint(f);        // positive float: u32-monotonic
            const uint32_t k = ((b + 512u) & 0xFFFFFC00u) | (idxb + (uint32_t)r);
            INS(k, q13, q14); INS(k, q12, q13); INS(k, q11, q12); INS(k, q10, q11);
            INS(k, q9,  q10); INS(k, q8,  q9);  INS(k, q7,  q8);  INS(k, q6,  q7);
            INS(k, q5,  q6);  INS(k, q4,  q5);  INS(k, q3,  q4);  INS(k, q2,  q3);
            INS(k, q1,  q2);  INS(k, q0,  q1);
            q0 = (q0 > k) ? q0 : k;
        }
    }

    // Store per-lane sorted-15 with reconstructed global j (uses this lane's g).
    #define STQ(t, qq) do { const uint32_t x_ = (qq); const uint32_t id_ = x_ & 1023u; \
        lv[wave][lane][t] = x_; \
        lx[wave][lane][t] = (t0 + (int)(id_ >> 2)) * 16 + g * 4 + (int)(id_ & 3u); } while (0)
    STQ(0, q0);  STQ(1, q1);  STQ(2, q2);  STQ(3, q3);  STQ(4, q4);
    STQ(5, q5);  STQ(6, q6);  STQ(7, q7);  STQ(8, q8);  STQ(9, q9);
    STQ(10, q10); STQ(11, q11); STQ(12, q12); STQ(13, q13); STQ(14, q14);
    #undef STQ
    __syncthreads();

    // 4-way merge of the lane-group lists for this i; write sorted 15.
    if (g == 0 && i < NROW) {
        int p0 = 0, p1 = 0, p2 = 0, p3 = 0;
        uint32_t v0 = lv[wave][li][0];
        uint32_t v1 = lv[wave][16 + li][0];
        uint32_t v2 = lv[wave][32 + li][0];
        uint32_t v3 = lv[wave][48 + li][0];
        uint32_t* ov = pkey + (((size_t)m * JC + chunk) * NROW + i) * KSEL;
        int*      oi = pidx + (((size_t)m * JC + chunk) * NROW + i) * KSEL;
        #pragma unroll
        for (int t = 0; t < KSEL; ++t) {
            uint32_t bv = v0; int bg = 0;
            if (v1 > bv) { bv = v1; bg = 1; }
            if (v2 > bv) { bv = v2; bg = 2; }
            if (v3 > bv) { bv = v3; bg = 3; }
            int oidx;
            if      (bg == 0) { oidx = lx[wave][li][p0];      p0++; v0 = p0 < KSEL ? lv[wave][li][p0]      : 0u; }
            else if (bg == 1) { oidx = lx[wave][16 + li][p1]; p1++; v1 = p1 < KSEL ? lv[wave][16 + li][p1] : 0u; }
            else if (bg == 2) { oidx = lx[wave][32 + li][p2]; p2++; v2 = p2 < KSEL ? lv[wave][32 + li][p2] : 0u; }
            else              { oidx = lx[wave][48 + li][p3]; p3++; v3 = p3 < KSEL ? lv[wave][48 + li][p3] : 0u; }
            ov[t] = bv; oi[t] = oidx;
        }
    }
}

// ---------------------------------------------------------------- merge + count
__global__ __launch_bounds__(256)
void knn_merge_count(const uint32_t* __restrict__ pkey, const int* __restrict__ pidx,
                     unsigned* __restrict__ counter)
{
    __shared__ int wsum[4];
    const int i    = blockIdx.x * 256 + threadIdx.x;
    const int lane = threadIdx.x & 63;
    const int wave = threadIdx.x >> 6;

    int cnt = 0;
    if (i < NROW) {
        int ida[KSEL], idb[KSEL];
        #pragma unroll
        for (int m = 0; m < 2; ++m) {
            const uint32_t* pv = pkey + (size_t)m * JC * NROW * KSEL;
            const int*      px = pidx + (size_t)m * JC * NROW * KSEL;
            const uint32_t* V0 = pv + ((size_t)0 * NROW + i) * KSEL;
            const uint32_t* V1 = pv + ((size_t)1 * NROW + i) * KSEL;
            const uint32_t* V2 = pv + ((size_t)2 * NROW + i) * KSEL;
            const uint32_t* V3 = pv + ((size_t)3 * NROW + i) * KSEL;
            const int* X0 = px + ((size_t)0 * NROW + i) * KSEL;
            const int* X1 = px + ((size_t)1 * NROW + i) * KSEL;
            const int* X2 = px + ((size_t)2 * NROW + i) * KSEL;
            const int* X3 = px + ((size_t)3 * NROW + i) * KSEL;
            int p0 = 0, p1 = 0, p2 = 0, p3 = 0;
            uint32_t v0 = V0[0], v1 = V1[0], v2 = V2[0], v3 = V3[0];
            int* out = (m == 0) ? ida : idb;
            #pragma unroll
            for (int t = 0; t < KSEL; ++t) {
                uint32_t bv = v0; int bg = 0;
                if (v1 > bv) { bv = v1; bg = 1; }
                if (v2 > bv) { bv = v2; bg = 2; }
                if (v3 > bv) { bv = v3; bg = 3; }
                if      (bg == 0) { out[t] = X0[p0]; p0++; v0 = p0 < KSEL ? V0[p0] : 0u; }
                else if (bg == 1) { out[t] = X1[p1]; p1++; v1 = p1 < KSEL ? V1[p1] : 0u; }
                else if (bg == 2) { out[t] = X2[p2]; p2++; v2 = p2 < KSEL ? V2[p2] : 0u; }
                else              { out[t] = X3[p3]; p3++; v3 = p3 < KSEL ? V3[p3] : 0u; }
            }
        }
        #pragma unroll
        for (int a = 0; a < KSEL; ++a)
            #pragma unroll
            for (int b = 0; b < KSEL; ++b)
                cnt += (ida[a] == idb[b]) ? 1 : 0;
    }

    #pragma unroll
    for (int off = 32; off; off >>= 1) cnt += __shfl_down(cnt, off);
    if (lane == 0) wsum[wave] = cnt;
    __syncthreads();
    if (threadIdx.x == 0)
        atomicAdd(counter, (unsigned)(wsum[0] + wsum[1] + wsum[2] + wsum[3]));
}

__global__ void knn_finalize(const unsigned* __restrict__ counter, float* __restrict__ out)
{
    out[0] = 1.0f - (float)(*counter) / (float)(NROW * KSEL);
}

// ---------------------------------------------------------------- launch
extern "C" void kernel_launch(void* const* d_in, const int* in_sizes, int n_in,
                              void* d_out, int out_size, void* d_ws, size_t ws_size,
                              hipStream_t stream)
{
    (void)in_sizes; (void)n_in; (void)out_size; (void)ws_size;
    const float* x0 = (const float*)d_in[0];
    const float* x1 = (const float*)d_in[1];
    float* out = (float*)d_out;

    char* ws = (char*)d_ws;
    size_t off = 0;
    bf16_t* xb = (bf16_t*)(ws + off); off += (size_t)2 * NP * DIM * sizeof(bf16_t);
    float*  sq = (float*)(ws + off);  off += (size_t)2 * NP * sizeof(float);
    off = (off + 255) & ~(size_t)255;
    uint32_t* pkey = (uint32_t*)(ws + off); off += (size_t)2 * JC * NROW * KSEL * sizeof(uint32_t);
    int*      pidx = (int*)(ws + off);      off += (size_t)2 * JC * NROW * KSEL * sizeof(int);
    off = (off + 255) & ~(size_t)255;
    unsigned* counter = (unsigned*)(ws + off);

    knn_convert<<<(2 * NP) / 4, 256, 0, stream>>>(x0, x1, xb, sq, counter);
    knn_topk<<<dim3(NP / 64, JC, 2), 256, 0, stream>>>(xb, sq, pkey, pidx);
    knn_merge_count<<<(NROW + 255) / 256, 256, 0, stream>>>(pkey, pidx, counter);
    knn_finalize<<<1, 1, 0, stream>>>(counter, out);
}